// Round 4
// baseline (711.731 us; speedup 1.0000x reference)
//
#include <hip/hip_runtime.h>
#include <hip/hip_bf16.h>

#define B_TOTAL 4096
#define MBATCH 16

typedef short short8 __attribute__((ext_vector_type(8)));
typedef float f32x4 __attribute__((ext_vector_type(4)));

__device__ __forceinline__ unsigned short rne_bf16(float x) {
    unsigned int u = __float_as_uint(x);
    unsigned int r = (u + 0x7fffu + ((u >> 16) & 1u)) >> 16;
    return (unsigned short)r;
}
__device__ __forceinline__ float bf16_to_f(unsigned short h) {
    return __uint_as_float(((unsigned int)h) << 16);
}
__device__ __forceinline__ unsigned int cvt2bf(float lo, float hi) {
    unsigned int r;
    asm("v_cvt_pk_bf16_f32 %0, %1, %2" : "=v"(r) : "v"(lo), "v"(hi));
    return r;   // low16 = bf16(lo), high16 = bf16(hi), RNE
}
__device__ __forceinline__ float fast_sigm(float x) {
    return __builtin_amdgcn_rcpf(1.0f + __expf(-x));
}
__device__ __forceinline__ float fast_tanh(float x) {
    return 1.0f - 2.0f * __builtin_amdgcn_rcpf(1.0f + __expf(2.0f * x));
}
__device__ __forceinline__ void cell_update(const f32x4 z, float& c, float& h) {
    const float ig = fast_sigm(z[0]);
    const float fg = fast_sigm(z[1]);
    const float gg = fast_tanh(z[2]);
    const float og = fast_sigm(z[3]);
    c = fg * c + ig * gg;
    h = og * fast_tanh(c);
}

// ---------------- Kernel A: neighbor mean ----------------
__global__ __launch_bounds__(256) void k_neighbor_mean(
    const float* __restrict__ matrix,   // [B,64,64]
    const float* __restrict__ features, // [B,64,6]
    float* __restrict__ upd)            // [B,64,6]
{
    __shared__ float adj[64][65];
    __shared__ float fx[64][6];
    const int b = blockIdx.x;
    const int tid = threadIdx.x;
    const float* mb_ = matrix + (size_t)b * 4096;
    for (int idx = tid; idx < 4096; idx += 256) adj[idx >> 6][idx & 63] = mb_[idx];
    const float* fb = features + (size_t)b * 384;
    for (int idx = tid; idx < 384; idx += 256) fx[idx / 6][idx % 6] = fb[idx];
    __syncthreads();
    if (tid < 64) {
        const int i = tid;
        float s0=0,s1=0,s2=0,s3=0,s4=0,s5=0,cnt=0;
        for (int j = 0; j < 64; j++) {
            float m = adj[i][j] > 0.0f ? 1.0f : 0.0f;
            cnt += m;
            s0 += m*fx[j][0]; s1 += m*fx[j][1]; s2 += m*fx[j][2];
            s3 += m*fx[j][3]; s4 += m*fx[j][4]; s5 += m*fx[j][5];
        }
        const float inv = 1.0f / (cnt + 1.0f);
        float* o = upd + (size_t)b * 384 + i * 6;
        o[0]=(s0+fx[i][0])*inv; o[1]=(s1+fx[i][1])*inv; o[2]=(s2+fx[i][2])*inv;
        o[3]=(s3+fx[i][3])*inv; o[4]=(s4+fx[i][4])*inv; o[5]=(s5+fx[i][5])*inv;
    }
}

// ---------------- Kernel W: weights -> A-fragment layout ----------------
// Aw[dir 2][mtg 32][kc 5][s 2][lane 64][e 8] bf16  (327680 ushorts)
// kc<4 : A'(n,k)=Wh[j][kc*32+8*lhi+e], s=0 hi / s=1 lo residual
// kc==4, s=0 (awU1): lhi0: e<6 Wi_hi, e6 bias_hi ; lhi1: e<6 Wi_hi ; lhi>=2: 0
// kc==4, s=1 (awU2): lhi0: e<6 Wi_lo, e6 bias_lo ; else 0
// n = mtg*16+(l&15), gate-interleaved: j = (n&3)*128 + (n>>2)
__global__ __launch_bounds__(256) void k_wprep2(
    const float* __restrict__ Wi_f, const float* __restrict__ Wh_f,
    const float* __restrict__ bi_f, const float* __restrict__ bh_f,
    const float* __restrict__ Wi_b, const float* __restrict__ Wh_b,
    const float* __restrict__ bi_b, const float* __restrict__ bh_b,
    unsigned short* __restrict__ Aw)
{
    const int idx = blockIdx.x * 256 + threadIdx.x;   // 0..327679
    const int dir = idx / 163840;
    int r   = idx % 163840;
    const int mtg = r / 5120;  r %= 5120;
    const int kc  = r / 1024;  r %= 1024;
    const int s   = r >> 9;
    const int l   = (r >> 3) & 63;
    const int e   = r & 7;
    const int lhi = l >> 4;
    const int n   = mtg * 16 + (l & 15);
    const int j   = (n & 3) * 128 + (n >> 2);
    const float* Wh = dir ? Wh_b : Wh_f;
    const float* Wi = dir ? Wi_b : Wi_f;
    const float* bi = dir ? bi_b : bi_f;
    const float* bh = dir ? bh_b : bh_f;
    float w = 0.0f;
    bool want_lo = (s == 1);
    if (kc < 4) {
        w = Wh[j * 128 + kc * 32 + 8 * lhi + e];
    } else {
        if (s == 0) {   // awU1: hi weights in both k-halves
            if (lhi == 0)      w = (e < 6) ? Wi[j * 6 + e] : (e == 6 ? bi[j] + bh[j] : 0.0f);
            else if (lhi == 1) w = (e < 6) ? Wi[j * 6 + e] : 0.0f;
            want_lo = false;
        } else {        // awU2: lo residuals, k 0..7 only
            if (lhi == 0)      w = (e < 6) ? Wi[j * 6 + e] : (e == 6 ? bi[j] + bh[j] : 0.0f);
            want_lo = true;
        }
    }
    const unsigned short hi = rne_bf16(w);
    Aw[idx] = want_lo ? rne_bf16(w - bf16_to_f(hi)) : hi;
}

// ---------------- Kernel B: MFMA bi-LSTM scan, 2 blocks/CU ----------------
// grid (256, 2), block 512 (8 waves). MBATCH=16 batches/block.
// Step s: reads h(s-1) from buf[(s+1)&1], writes h(s) to buf[s&1], one barrier/step.
__global__ __launch_bounds__(512, 4) void k_lstm4(
    const float* __restrict__ upd,          // [4096][64][6]
    const unsigned short* __restrict__ Aw,  // [2][32][5][2][64][8]
    float* __restrict__ hout)               // [2][4096][128]
{
    // H: byte = plane*8192 + buf*4096 + b*256 + swz_chunk*16 + (hu&7)*2   (16 KB)
    __shared__ unsigned short H[2][2][2048];
    // Ust: byte = t*512 + lane*16 ; lanes 0-15 = u_hi(+1.0@e6), 16-31 = u_lo (32 KB)
    __shared__ unsigned short Ust[64 * 32 * 8];
    const int tid  = threadIdx.x;
    const int wave = tid >> 6;
    const int lane = tid & 63;
    const int dir  = blockIdx.y;
    const int b0   = blockIdx.x * MBATCH;
    const int l15  = lane & 15;
    const int lhi  = lane >> 4;
    char* Hb = (char*)H;
    char* Ub = (char*)Ust;

    // persistent weight fragments: 4mt x (4kc x 2) + 2 awU = 136 regs
    short8 aw[4][4][2], awU[4][2];
    {
        const unsigned short* base = Aw + (size_t)dir * 163840;
        #pragma unroll
        for (int mt = 0; mt < 4; mt++) {
            const int mtg = wave * 4 + mt;
            #pragma unroll
            for (int kc = 0; kc < 4; kc++)
                #pragma unroll
                for (int s = 0; s < 2; s++)
                    aw[mt][kc][s] = *(const short8*)(base + (((size_t)(mtg * 5 + kc) * 2 + s) * 64 + lane) * 8);
            #pragma unroll
            for (int s = 0; s < 2; s++)
                awU[mt][s] = *(const short8*)(base + (((size_t)(mtg * 5 + 4) * 2 + s) * 64 + lane) * 8);
        }
    }

    // stage u fragments for all 64 steps (hi + lo residual planes)
    for (int idx = tid; idx < 1024; idx += 512) {
        const int b = idx >> 6, t = idx & 63;
        const float2* p = (const float2*)(upd + (size_t)(b0 + b) * 384 + t * 6);
        const float2 a0 = p[0], a1 = p[1], a2 = p[2];
        const unsigned p0 = cvt2bf(a0.x, a0.y);
        const unsigned p1 = cvt2bf(a1.x, a1.y);
        const unsigned p2 = cvt2bf(a2.x, a2.y);
        const float r0 = a0.x - __uint_as_float(p0 << 16);
        const float r1 = a0.y - __uint_as_float(p0 & 0xffff0000u);
        const float r2 = a1.x - __uint_as_float(p1 << 16);
        const float r3 = a1.y - __uint_as_float(p1 & 0xffff0000u);
        const float r4 = a2.x - __uint_as_float(p2 << 16);
        const float r5 = a2.y - __uint_as_float(p2 & 0xffff0000u);
        int4 hi4, lo4;
        hi4.x = (int)p0; hi4.y = (int)p1; hi4.z = (int)p2; hi4.w = 0x3f80;
        lo4.x = (int)cvt2bf(r0, r1); lo4.y = (int)cvt2bf(r2, r3); lo4.z = (int)cvt2bf(r4, r5); lo4.w = 0;
        *(int4*)(Ub + t * 512 + b * 16)       = hi4;
        *(int4*)(Ub + t * 512 + 256 + b * 16) = lo4;
    }

    // LDS addresses (hi plane; lo = +8192; buf toggle = XOR 0x1000)
    int raddr[4], waddr[4];
    #pragma unroll
    for (int kc = 0; kc < 4; kc++)
        raddr[kc] = l15 * 256 + (((kc * 4 + lhi) ^ (l15 & 7)) << 4) + 4096;  // rbuf=1 at s=0
    #pragma unroll
    for (int mt = 0; mt < 4; mt++) {
        const int hu = wave * 16 + mt * 4 + lhi;
        waddr[mt] = l15 * 256 + ((((hu >> 3) ^ (l15 & 7))) << 4) + (hu & 7) * 2;  // wbuf=0 at s=0
    }
    const int uaddr = (lane & 31) * 16;

    // zero buf1 of both planes (read target of step 0)
    for (int i = tid; i < 1024; i += 512) {
        ((int*)Hb)[1024 + i] = 0;   // hi buf1
        ((int*)Hb)[3072 + i] = 0;   // lo buf1
    }
    float c[4];
    #pragma unroll
    for (int p = 0; p < 4; p++) c[p] = 0.0f;

    __syncthreads();

    const f32x4 zero4 = {0.0f, 0.0f, 0.0f, 0.0f};

    #pragma unroll 1
    for (int s = 0; s < 64; ++s) {
        const int t = dir ? (63 - s) : s;

        // u fragment (prestaged); same frag feeds both u-MFMAs (awU2 is 0 in other lanes)
        const short8 f1 = *(const short8*)(Ub + t * 512 + uaddr);

        __builtin_amdgcn_s_setprio(1);
        f32x4 acc[4];
        #pragma unroll
        for (int kc = 0; kc < 4; kc++) {
            const short8 fh = *(const short8*)(Hb + raddr[kc]);
            const short8 fl = *(const short8*)(Hb + raddr[kc] + 8192);
            #pragma unroll
            for (int mt = 0; mt < 4; mt++) {
                f32x4 a = __builtin_amdgcn_mfma_f32_16x16x32_bf16(aw[mt][kc][0], fh, kc == 0 ? zero4 : acc[mt], 0, 0, 0);
                a = __builtin_amdgcn_mfma_f32_16x16x32_bf16(aw[mt][kc][0], fl, a, 0, 0, 0);
                acc[mt] = __builtin_amdgcn_mfma_f32_16x16x32_bf16(aw[mt][kc][1], fh, a, 0, 0, 0);
            }
        }
        #pragma unroll
        for (int mt = 0; mt < 4; mt++) {
            acc[mt] = __builtin_amdgcn_mfma_f32_16x16x32_bf16(awU[mt][0], f1, acc[mt], 0, 0, 0);
            acc[mt] = __builtin_amdgcn_mfma_f32_16x16x32_bf16(awU[mt][1], f1, acc[mt], 0, 0, 0);
        }
        __builtin_amdgcn_s_setprio(0);

        // lane-local cell updates: the 4 D-regs of acc[mt] are gates i,f,g,o of (b=l15, hu)
        #pragma unroll
        for (int mt = 0; mt < 4; mt++) {
            float h;
            cell_update(acc[mt], c[mt], h);
            if (s < 63) {
                const unsigned pk = cvt2bf(h, h);
                const float res = h - __uint_as_float(pk << 16);
                const unsigned pk2 = cvt2bf(res, res);
                *(unsigned short*)(Hb + waddr[mt])        = (unsigned short)pk;
                *(unsigned short*)(Hb + waddr[mt] + 8192) = (unsigned short)pk2;
            } else {
                const int hu = wave * 16 + mt * 4 + lhi;
                hout[((size_t)dir * B_TOTAL + b0 + l15) * 128 + hu] = h;
            }
        }

        if (s < 63) {
            #pragma unroll
            for (int kc = 0; kc < 4; kc++) raddr[kc] ^= 0x1000;
            #pragma unroll
            for (int mt = 0; mt < 4; mt++) waddr[mt] ^= 0x1000;
        }
        __syncthreads();
    }
}

// ---------------- Kernel C: final FC ----------------
__global__ __launch_bounds__(256) void k_final(
    const float* __restrict__ hout,        // [2][B][128]
    const float* __restrict__ device_idx,  // [B]
    const float* __restrict__ fc_w,        // [257]
    const float* __restrict__ fc_b,        // [1]
    float* __restrict__ y)                 // [B]
{
    const int wave = threadIdx.x >> 6;
    const int lane = threadIdx.x & 63;
    const int b = blockIdx.x * 4 + wave;
    const float* hf = hout + (size_t)b * 128;
    const float* hb = hout + ((size_t)B_TOTAL + b) * 128;
    float p = fc_w[1 + lane]        * hf[lane]
            + fc_w[1 + 64 + lane]   * hf[64 + lane]
            + fc_w[129 + lane]      * hb[lane]
            + fc_w[129 + 64 + lane] * hb[64 + lane];
    #pragma unroll
    for (int off = 32; off; off >>= 1) p += __shfl_xor(p, off, 64);
    if (lane == 0) y[b] = p + fc_w[0] * device_idx[b] + fc_b[0];
}

extern "C" void kernel_launch(void* const* d_in, const int* in_sizes, int n_in,
                              void* d_out, int out_size, void* d_ws, size_t ws_size,
                              hipStream_t stream) {
    const float* device_idx = (const float*)d_in[0];
    const float* matrix     = (const float*)d_in[1];
    const float* features   = (const float*)d_in[2];
    const float* Wi_f = (const float*)d_in[3];
    const float* Wh_f = (const float*)d_in[4];
    const float* bi_f = (const float*)d_in[5];
    const float* bh_f = (const float*)d_in[6];
    const float* Wi_b = (const float*)d_in[7];
    const float* Wh_b = (const float*)d_in[8];
    const float* bi_b = (const float*)d_in[9];
    const float* bh_b = (const float*)d_in[10];
    const float* fc_w = (const float*)d_in[11];
    const float* fc_b = (const float*)d_in[12];
    float* out = (float*)d_out;

    float* ws = (float*)d_ws;
    float*          upd  = ws;                               // 1,572,864 floats
    unsigned short* Aw   = (unsigned short*)(ws + 1572864);  // 327,680 ushorts
    float*          hout = ws + 1736704;                     // 1,048,576 floats

    hipLaunchKernelGGL(k_neighbor_mean, dim3(B_TOTAL), dim3(256), 0, stream,
                       matrix, features, upd);
    hipLaunchKernelGGL(k_wprep2, dim3(1280), dim3(256), 0, stream,
                       Wi_f, Wh_f, bi_f, bh_f, Wi_b, Wh_b, bi_b, bh_b, Aw);
    hipLaunchKernelGGL(k_lstm4, dim3(B_TOTAL / MBATCH, 2), dim3(512), 0, stream,
                       upd, Aw, hout);
    hipLaunchKernelGGL(k_final, dim3(B_TOTAL / 4), dim3(256), 0, stream,
                       hout, device_idx, fc_w, fc_b, out);
}

// Round 5
// 204.056 us; speedup vs baseline: 3.4879x; 3.4879x over previous
//
#include <hip/hip_runtime.h>
#include <hip/hip_bf16.h>

#define B_TOTAL 4096
#define MBATCH 16

typedef short short8 __attribute__((ext_vector_type(8)));
typedef float f32x4 __attribute__((ext_vector_type(4)));

__device__ __forceinline__ unsigned short rne_bf16(float x) {
    unsigned int u = __float_as_uint(x);
    unsigned int r = (u + 0x7fffu + ((u >> 16) & 1u)) >> 16;
    return (unsigned short)r;
}
__device__ __forceinline__ float bf16_to_f(unsigned short h) {
    return __uint_as_float(((unsigned int)h) << 16);
}
__device__ __forceinline__ unsigned int cvt2bf(float lo, float hi) {
    unsigned int r;
    asm("v_cvt_pk_bf16_f32 %0, %1, %2" : "=v"(r) : "v"(lo), "v"(hi));
    return r;   // low16 = bf16(lo), high16 = bf16(hi), RNE
}
__device__ __forceinline__ float fast_sigm(float x) {
    return __builtin_amdgcn_rcpf(1.0f + __expf(-x));
}
__device__ __forceinline__ float fast_tanh(float x) {
    return 1.0f - 2.0f * __builtin_amdgcn_rcpf(1.0f + __expf(2.0f * x));
}
__device__ __forceinline__ void cell_update(const f32x4 z, float& c, float& h) {
    const float ig = fast_sigm(z[0]);
    const float fg = fast_sigm(z[1]);
    const float gg = fast_tanh(z[2]);
    const float og = fast_sigm(z[3]);
    c = fg * c + ig * gg;
    h = og * fast_tanh(c);
}

// ---------------- Kernel A: neighbor mean ----------------
__global__ __launch_bounds__(256) void k_neighbor_mean(
    const float* __restrict__ matrix,   // [B,64,64]
    const float* __restrict__ features, // [B,64,6]
    float* __restrict__ upd)            // [B,64,6]
{
    __shared__ float adj[64][65];
    __shared__ float fx[64][6];
    const int b = blockIdx.x;
    const int tid = threadIdx.x;
    const float* mb_ = matrix + (size_t)b * 4096;
    for (int idx = tid; idx < 4096; idx += 256) adj[idx >> 6][idx & 63] = mb_[idx];
    const float* fb = features + (size_t)b * 384;
    for (int idx = tid; idx < 384; idx += 256) fx[idx / 6][idx % 6] = fb[idx];
    __syncthreads();
    if (tid < 64) {
        const int i = tid;
        float s0=0,s1=0,s2=0,s3=0,s4=0,s5=0,cnt=0;
        for (int j = 0; j < 64; j++) {
            float m = adj[i][j] > 0.0f ? 1.0f : 0.0f;
            cnt += m;
            s0 += m*fx[j][0]; s1 += m*fx[j][1]; s2 += m*fx[j][2];
            s3 += m*fx[j][3]; s4 += m*fx[j][4]; s5 += m*fx[j][5];
        }
        const float inv = 1.0f / (cnt + 1.0f);
        float* o = upd + (size_t)b * 384 + i * 6;
        o[0]=(s0+fx[i][0])*inv; o[1]=(s1+fx[i][1])*inv; o[2]=(s2+fx[i][2])*inv;
        o[3]=(s3+fx[i][3])*inv; o[4]=(s4+fx[i][4])*inv; o[5]=(s5+fx[i][5])*inv;
    }
}

// ---------------- Kernel W: weights -> A-fragment layouts ----------------
// AwHi/AwLo [dir 2][mtg 32][kc 4][lane 64][e 8] bf16 : Wh hi / lo-residual A-fragments
//   n = mtg*16 + (l&15), j = (n&3)*128 + (n>>2), k = kc*32 + 8*(l>>4) + e
// AwU [dir 2][mtg 32][lane 64][e 8] bf16 : Wi hi; nonzero only l>>4==0 && e<6
// Bq  [dir 2][n 512] f32 : bi[j]+bh[j]  (exact fp32 bias, applied as acc-init)
__global__ __launch_bounds__(256) void k_wprep3(
    const float* __restrict__ Wi_f, const float* __restrict__ Wh_f,
    const float* __restrict__ bi_f, const float* __restrict__ bh_f,
    const float* __restrict__ Wi_b, const float* __restrict__ Wh_b,
    const float* __restrict__ bi_b, const float* __restrict__ bh_b,
    unsigned short* __restrict__ AwHi, unsigned short* __restrict__ AwLo,
    unsigned short* __restrict__ AwU, float* __restrict__ BqO)
{
    const int idx = blockIdx.x * 256 + threadIdx.x;   // 0..295935
    if (idx < 262144) {
        const bool lo = idx >= 131072;
        const int i2 = idx & 131071;
        const int dir = i2 >> 16;
        const int r = i2 & 65535;
        const int mtg = r >> 11, kc = (r >> 9) & 3, l = (r >> 3) & 63, e = r & 7;
        const int n = mtg * 16 + (l & 15);
        const int j = ((n & 3) << 7) + (n >> 2);
        const int k = kc * 32 + 8 * (l >> 4) + e;
        const float w = (dir ? Wh_b : Wh_f)[j * 128 + k];
        const unsigned short hi = rne_bf16(w);
        if (lo) AwLo[i2] = rne_bf16(w - bf16_to_f(hi));
        else    AwHi[i2] = hi;
    } else if (idx < 294912) {
        const int i2 = idx - 262144;       // 0..32767
        const int dir = i2 >> 14;
        const int r = i2 & 16383;
        const int mtg = r >> 9, l = (r >> 3) & 63, e = r & 7;
        const int n = mtg * 16 + (l & 15);
        const int j = ((n & 3) << 7) + (n >> 2);
        float w = 0.0f;
        if ((l >> 4) == 0 && e < 6) w = (dir ? Wi_b : Wi_f)[j * 6 + e];
        AwU[i2] = rne_bf16(w);
    } else if (idx < 295936) {
        const int i2 = idx - 294912;       // 0..1023
        const int dir = i2 >> 9;
        const int n = i2 & 511;
        const int j = ((n & 3) << 7) + (n >> 2);
        BqO[i2] = (dir ? bi_b : bi_f)[j] + (dir ? bh_b : bh_f)[j];
    }
}

// ---------------- Kernel B: MFMA bi-LSTM scan, 16 waves, 4 waves/SIMD ----------------
// grid (256, 2), block 1024 (16 waves). Block = 16 batches, one dir.
// Wave owns mtg {2w, 2w+1} (8 hu) x 16 batches. ~113 VGPR -> 4 waves/SIMD, no spill.
__global__ __launch_bounds__(1024) void k_lstm5(
    const float* __restrict__ upd,           // [4096][64][6]
    const unsigned short* __restrict__ AwHi, // [2][32][4][64][8]
    const unsigned short* __restrict__ AwLo, // [2][32][4][64][8]
    const unsigned short* __restrict__ AwU,  // [2][32][64][8]
    const float* __restrict__ Bq,            // [2][512]
    float* __restrict__ hout)                // [2][4096][128]
{
    // H: byte = plane*8192 + buf*4096 + b*256 + swz_chunk*16 + (hu&7)*2   (16 KB)
    __shared__ unsigned short H[2][2][2048];
    // Ust: byte = t*256 + b*16 ; 16B u_hi frag per (t,b); +16B zero pad at 16384
    __shared__ unsigned short Ust[64 * 16 * 8 + 8];
    __shared__ float Lbias[512];
    const int tid  = threadIdx.x;
    const int wave = tid >> 6;
    const int lane = tid & 63;
    const int dir  = blockIdx.y;
    const int b0   = blockIdx.x * MBATCH;
    const int l15  = lane & 15;
    const int lhi  = lane >> 4;
    char* Hb = (char*)H;
    char* Ub = (char*)Ust;

    // persistent weights: 2mt x 4kc x {hi,lo} + 2 awu = 72 VGPRs
    short8 awh[2][4], awl[2][4], awu[2];
    const int mtg0 = 2 * wave;
    #pragma unroll
    for (int mt = 0; mt < 2; mt++) {
        #pragma unroll
        for (int kc = 0; kc < 4; kc++) {
            const int f = ((mtg0 + mt) * 4 + kc) * 512 + lane * 8;
            awh[mt][kc] = *(const short8*)(AwHi + dir * 65536 + f);
            awl[mt][kc] = *(const short8*)(AwLo + dir * 65536 + f);
        }
        awu[mt] = *(const short8*)(AwU + dir * 16384 + (mtg0 + mt) * 512 + lane * 8);
    }

    // stage bias (fp32, exact)
    if (tid < 512) Lbias[tid] = Bq[dir * 512 + tid];

    // stage u hi-fragments for all 64 steps: [t][b] 16B = {u0..u5, 0, 0} bf16
    {
        const int t = tid >> 4, b = tid & 15;   // tid < 1024 covers all
        const float2* p = (const float2*)(upd + (size_t)(b0 + b) * 384 + t * 6);
        const float2 a0 = p[0], a1 = p[1], a2 = p[2];
        int4 hi4;
        hi4.x = (int)cvt2bf(a0.x, a0.y);
        hi4.y = (int)cvt2bf(a1.x, a1.y);
        hi4.z = (int)cvt2bf(a2.x, a2.y);
        hi4.w = 0;
        *(int4*)(Ub + t * 256 + b * 16) = hi4;
    }
    if (tid == 0) { int4 z = {0,0,0,0}; *(int4*)(Ub + 16384) = z; }

    // zero buf1 of both h planes (read target of step 0)
    ((int*)Hb)[1024 + tid] = 0;   // hi buf1 (bytes 4096..8191)
    ((int*)Hb)[3072 + tid] = 0;   // lo buf1 (bytes 12288..16383)

    // LDS addresses (hi plane, buf toggled by XOR 0x1000; lo plane = +8192 imm)
    int raddr[4], waddr[2];
    #pragma unroll
    for (int kc = 0; kc < 4; kc++)
        raddr[kc] = l15 * 256 + (((kc * 4 + lhi) ^ (l15 & 7)) << 4) + 4096;  // rbuf=1 at s=0
    const int hu0 = 8 * wave + lhi;       // hu for mt=0
    const int hu1 = hu0 + 4;              // hu for mt=1
    waddr[0] = l15 * 256 + (((hu0 >> 3) ^ (l15 & 7)) << 4) + (hu0 & 7) * 2;  // wbuf=0 at s=0
    waddr[1] = l15 * 256 + (((hu1 >> 3) ^ (l15 & 7)) << 4) + (hu1 & 7) * 2;
    const int ba0 = hu0 * 4, ba1 = hu1 * 4;   // Lbias float index of gate0

    float c0 = 0.0f, c1 = 0.0f;
    __syncthreads();

    #pragma unroll 1
    for (int s = 0; s < 64; ++s) {
        const int t = dir ? (63 - s) : s;

        // u fragment (prestaged); lanes lhi>0 read the zero pad (k>=8 contributes 0)
        const int ua = (lhi == 0) ? (t * 256 + l15 * 16) : 16384;
        const short8 f1 = *(const short8*)(Ub + ua);

        // acc init = exact fp32 bias (D reg i = gate i of (b=l15, hu))
        f32x4 acc0 = *(const f32x4*)&Lbias[ba0];
        f32x4 acc1 = *(const f32x4*)&Lbias[ba1];

        __builtin_amdgcn_s_setprio(1);
        #pragma unroll
        for (int kc = 0; kc < 4; kc++) {
            const short8 fh = *(const short8*)(Hb + raddr[kc]);
            const short8 fl = *(const short8*)(Hb + raddr[kc] + 8192);
            acc0 = __builtin_amdgcn_mfma_f32_16x16x32_bf16(awh[0][kc], fh, acc0, 0, 0, 0);
            acc0 = __builtin_amdgcn_mfma_f32_16x16x32_bf16(awh[0][kc], fl, acc0, 0, 0, 0);
            acc0 = __builtin_amdgcn_mfma_f32_16x16x32_bf16(awl[0][kc], fh, acc0, 0, 0, 0);
            acc1 = __builtin_amdgcn_mfma_f32_16x16x32_bf16(awh[1][kc], fh, acc1, 0, 0, 0);
            acc1 = __builtin_amdgcn_mfma_f32_16x16x32_bf16(awh[1][kc], fl, acc1, 0, 0, 0);
            acc1 = __builtin_amdgcn_mfma_f32_16x16x32_bf16(awl[1][kc], fh, acc1, 0, 0, 0);
        }
        acc0 = __builtin_amdgcn_mfma_f32_16x16x32_bf16(awu[0], f1, acc0, 0, 0, 0);
        acc1 = __builtin_amdgcn_mfma_f32_16x16x32_bf16(awu[1], f1, acc1, 0, 0, 0);
        __builtin_amdgcn_s_setprio(0);

        // lane-local cell updates
        float h0, h1;
        cell_update(acc0, c0, h0);
        cell_update(acc1, c1, h1);
        if (s < 63) {
            unsigned pk = cvt2bf(h0, h0);
            float res = h0 - __uint_as_float(pk << 16);
            unsigned pk2 = cvt2bf(res, res);
            *(unsigned short*)(Hb + waddr[0])        = (unsigned short)pk;
            *(unsigned short*)(Hb + waddr[0] + 8192) = (unsigned short)pk2;
            pk = cvt2bf(h1, h1);
            res = h1 - __uint_as_float(pk << 16);
            pk2 = cvt2bf(res, res);
            *(unsigned short*)(Hb + waddr[1])        = (unsigned short)pk;
            *(unsigned short*)(Hb + waddr[1] + 8192) = (unsigned short)pk2;
            raddr[0] ^= 0x1000; raddr[1] ^= 0x1000;
            raddr[2] ^= 0x1000; raddr[3] ^= 0x1000;
            waddr[0] ^= 0x1000; waddr[1] ^= 0x1000;
        } else {
            float* o = hout + ((size_t)dir * B_TOTAL + b0 + l15) * 128;
            o[hu0] = h0;
            o[hu1] = h1;
        }
        __syncthreads();
    }
}

// ---------------- Kernel C: final FC ----------------
__global__ __launch_bounds__(256) void k_final(
    const float* __restrict__ hout,        // [2][B][128]
    const float* __restrict__ device_idx,  // [B]
    const float* __restrict__ fc_w,        // [257]
    const float* __restrict__ fc_b,        // [1]
    float* __restrict__ y)                 // [B]
{
    const int wave = threadIdx.x >> 6;
    const int lane = threadIdx.x & 63;
    const int b = blockIdx.x * 4 + wave;
    const float* hf = hout + (size_t)b * 128;
    const float* hb = hout + ((size_t)B_TOTAL + b) * 128;
    float p = fc_w[1 + lane]        * hf[lane]
            + fc_w[1 + 64 + lane]   * hf[64 + lane]
            + fc_w[129 + lane]      * hb[lane]
            + fc_w[129 + 64 + lane] * hb[64 + lane];
    #pragma unroll
    for (int off = 32; off; off >>= 1) p += __shfl_xor(p, off, 64);
    if (lane == 0) y[b] = p + fc_w[0] * device_idx[b] + fc_b[0];
}

extern "C" void kernel_launch(void* const* d_in, const int* in_sizes, int n_in,
                              void* d_out, int out_size, void* d_ws, size_t ws_size,
                              hipStream_t stream) {
    const float* device_idx = (const float*)d_in[0];
    const float* matrix     = (const float*)d_in[1];
    const float* features   = (const float*)d_in[2];
    const float* Wi_f = (const float*)d_in[3];
    const float* Wh_f = (const float*)d_in[4];
    const float* bi_f = (const float*)d_in[5];
    const float* bh_f = (const float*)d_in[6];
    const float* Wi_b = (const float*)d_in[7];
    const float* Wh_b = (const float*)d_in[8];
    const float* bi_b = (const float*)d_in[9];
    const float* bh_b = (const float*)d_in[10];
    const float* fc_w = (const float*)d_in[11];
    const float* fc_b = (const float*)d_in[12];
    float* out = (float*)d_out;

    float* ws = (float*)d_ws;
    float*          upd  = ws;                               // 1,572,864 floats
    unsigned short* AwHi = (unsigned short*)(ws + 1572864);  // 131,072 ushorts
    unsigned short* AwLo = (unsigned short*)(ws + 1638400);  // 131,072 ushorts
    unsigned short* AwU  = (unsigned short*)(ws + 1703936);  //  32,768 ushorts
    float*          Bq   = ws + 1720320;                     //   1,024 floats
    float*          hout = ws + 1721344;                     // 1,048,576 floats

    hipLaunchKernelGGL(k_neighbor_mean, dim3(B_TOTAL), dim3(256), 0, stream,
                       matrix, features, upd);
    hipLaunchKernelGGL(k_wprep3, dim3(1156), dim3(256), 0, stream,
                       Wi_f, Wh_f, bi_f, bh_f, Wi_b, Wh_b, bi_b, bh_b,
                       AwHi, AwLo, AwU, Bq);
    hipLaunchKernelGGL(k_lstm5, dim3(B_TOTAL / MBATCH, 2), dim3(1024), 0, stream,
                       upd, AwHi, AwLo, AwU, Bq, hout);
    hipLaunchKernelGGL(k_final, dim3(B_TOTAL / 4), dim3(256), 0, stream,
                       hout, device_idx, fc_w, fc_b, out);
}

// Round 6
// 196.740 us; speedup vs baseline: 3.6176x; 1.0372x over previous
//
#include <hip/hip_runtime.h>
#include <hip/hip_bf16.h>

#define B_TOTAL 4096

typedef short short8 __attribute__((ext_vector_type(8)));
typedef float f32x4 __attribute__((ext_vector_type(4)));
typedef int   i32x4 __attribute__((ext_vector_type(4)));

__device__ __forceinline__ unsigned short rne_bf16(float x) {
    unsigned int u = __float_as_uint(x);
    unsigned int r = (u + 0x7fffu + ((u >> 16) & 1u)) >> 16;
    return (unsigned short)r;
}
__device__ __forceinline__ unsigned int cvt2bf(float lo, float hi) {
    unsigned int r;
    asm("v_cvt_pk_bf16_f32 %0, %1, %2" : "=v"(r) : "v"(lo), "v"(hi));
    return r;
}
__device__ __forceinline__ float fast_sigm(float x) {
    return __builtin_amdgcn_rcpf(1.0f + __expf(-x));
}
__device__ __forceinline__ float fast_tanh(float x) {
    return 1.0f - 2.0f * __builtin_amdgcn_rcpf(1.0f + __expf(2.0f * x));
}
__device__ __forceinline__ void cell_update(const f32x4 z, float& c, float& h) {
    const float ig = fast_sigm(z[0]);
    const float fg = fast_sigm(z[1]);
    const float gg = fast_tanh(z[2]);
    const float og = fast_sigm(z[3]);
    c = fg * c + ig * gg;
    h = og * fast_tanh(c);
}

// ---------------- Kernel A: neighbor mean ----------------
__global__ __launch_bounds__(256) void k_neighbor_mean(
    const float* __restrict__ matrix,   // [B,64,64]
    const float* __restrict__ features, // [B,64,6]
    float* __restrict__ upd)            // [B,64,6]
{
    __shared__ float adj[64][65];
    __shared__ float fx[64][6];
    const int b = blockIdx.x;
    const int tid = threadIdx.x;
    const float* mb_ = matrix + (size_t)b * 4096;
    for (int idx = tid; idx < 4096; idx += 256) adj[idx >> 6][idx & 63] = mb_[idx];
    const float* fb = features + (size_t)b * 384;
    for (int idx = tid; idx < 384; idx += 256) fx[idx / 6][idx % 6] = fb[idx];
    __syncthreads();
    if (tid < 64) {
        const int i = tid;
        float s0=0,s1=0,s2=0,s3=0,s4=0,s5=0,cnt=0;
        for (int j = 0; j < 64; j++) {
            float m = adj[i][j] > 0.0f ? 1.0f : 0.0f;
            cnt += m;
            s0 += m*fx[j][0]; s1 += m*fx[j][1]; s2 += m*fx[j][2];
            s3 += m*fx[j][3]; s4 += m*fx[j][4]; s5 += m*fx[j][5];
        }
        const float inv = 1.0f / (cnt + 1.0f);
        float* o = upd + (size_t)b * 384 + i * 6;
        o[0]=(s0+fx[i][0])*inv; o[1]=(s1+fx[i][1])*inv; o[2]=(s2+fx[i][2])*inv;
        o[3]=(s3+fx[i][3])*inv; o[4]=(s4+fx[i][4])*inv; o[5]=(s5+fx[i][5])*inv;
    }
}

// ---------------- Kernel W: weights -> i8 digit A-fragments ----------------
// Wd1/Wd2 [dir 2][mtg 32][kc 2][lane 64][e 16] i8:
//   n = mtg*16 + (lane&15), j = (n&3)*128 + (n>>2)   (n = 4*hu + gate)
//   k_store = kc*64 + 16*(lane>>4) + e; hu_src = 8*(ks>>3) + ((ks&7)>>1) + 4*(ks&1)
//   w = Wh[j*128 + hu_src];  w1 = rint(w*2^10), w2 = rint((w*2^10 - w1)*2^7)
// AwU [dir 2][mtg 32][lane 64][e 8] bf16 : Wi hi (nonzero only lane>>4==0 && e<6)
// Bq  [dir 2][n 512] f32 : bi[j]+bh[j]
__global__ __launch_bounds__(256) void k_wprep4(
    const float* __restrict__ Wi_f, const float* __restrict__ Wh_f,
    const float* __restrict__ bi_f, const float* __restrict__ bh_f,
    const float* __restrict__ Wi_b, const float* __restrict__ Wh_b,
    const float* __restrict__ bi_b, const float* __restrict__ bh_b,
    signed char* __restrict__ Wd1, signed char* __restrict__ Wd2,
    unsigned short* __restrict__ AwU, float* __restrict__ BqO)
{
    const int idx = blockIdx.x * 256 + threadIdx.x;   // 0..164863
    if (idx < 131072) {
        const int dir = idx >> 16;
        const int r = idx & 65535;
        const int mtg = r >> 11;
        const int kc  = (r >> 10) & 1;
        const int l   = (r >> 4) & 63;
        const int e   = r & 15;
        const int n = mtg * 16 + (l & 15);
        const int j = ((n & 3) << 7) + (n >> 2);
        const int ks = kc * 64 + 16 * (l >> 4) + e;   // 0..127
        const int hu = 8 * (ks >> 3) + ((ks & 7) >> 1) + 4 * (ks & 1);
        const float w = (dir ? Wh_b : Wh_f)[j * 128 + hu];
        const float a = w * 1024.0f;
        const float r1 = rintf(a);
        Wd1[idx] = (signed char)(int)r1;
        Wd2[idx] = (signed char)(int)rintf((a - r1) * 128.0f);
    } else if (idx < 163840) {
        const int i2 = idx - 131072;       // 0..32767
        const int dir = i2 >> 14;
        const int r = i2 & 16383;
        const int mtg = r >> 9, l = (r >> 3) & 63, e = r & 7;
        const int n = mtg * 16 + (l & 15);
        const int j = ((n & 3) << 7) + (n >> 2);
        float w = 0.0f;
        if ((l >> 4) == 0 && e < 6) w = (dir ? Wi_b : Wi_f)[j * 6 + e];
        AwU[i2] = rne_bf16(w);
    } else if (idx < 164864) {
        const int i2 = idx - 163840;       // 0..1023
        const int dir = i2 >> 9;
        const int n = i2 & 511;
        const int j = ((n & 3) << 7) + (n >> 2);
        BqO[i2] = (dir ? bi_b : bi_f)[j] + (dir ? bh_b : bh_f)[j];
    }
}

// ---------------- Kernel B: i8 digit-pair MFMA bi-LSTM, 2-group interleave ----------------
// grid (128, 2), block 1024 (16 waves), 1 block/CU, one round.
// Wave owns mtg {2w,2w+1} (hu 8w..8w+7) x 32 batches (two 16-batch groups).
__global__ __launch_bounds__(1024) void k_lstm7(
    const float* __restrict__ upd,          // [4096][64][6]
    const signed char* __restrict__ Wd1,    // [2][32][2][64][16]
    const signed char* __restrict__ Wd2,    // [2][32][2][64][16]
    const unsigned short* __restrict__ AwU, // [2][32][64][8]
    const float* __restrict__ Bq,           // [2][512]
    float* __restrict__ hout)               // [2][4096][128]
{
    // H: byte = g*16384 + digit*8192 + buf*4096 + row(l15)*144 + col
    //   col: i8 h-digit at store-column p(hu) = 8*(hu>>3) + 2*(hu&3) + ((hu>>2)&1)
    __shared__ char Hb[32768];
    // Ust: byte = t*512 + b*16 : bf16x8 u-frag {u0..u5,0,0} per (t, b 0..31)
    __shared__ char Ub[32768];
    const int tid  = threadIdx.x;
    const int wave = tid >> 6;
    const int lane = tid & 63;
    const int dir  = blockIdx.y;
    const int b0   = blockIdx.x * 32;
    const int l15  = lane & 15;
    const int lhi  = lane >> 4;

    // persistent weights: 16+16 i32x4 digits + 2 bf16 u-frags + 2 f32x4 bias = 56 VGPRs
    i32x4 wd1[2][2], wd2[2][2];
    short8 awu[2];
    f32x4 bias[2];
    #pragma unroll
    for (int mt = 0; mt < 2; mt++) {
        const int mtg = 2 * wave + mt;
        #pragma unroll
        for (int kc = 0; kc < 2; kc++) {
            wd1[mt][kc] = *(const i32x4*)(Wd1 + dir * 65536 + mtg * 2048 + kc * 1024 + lane * 16);
            wd2[mt][kc] = *(const i32x4*)(Wd2 + dir * 65536 + mtg * 2048 + kc * 1024 + lane * 16);
        }
        awu[mt] = *(const short8*)(AwU + dir * 16384 + mtg * 512 + lane * 8);
        bias[mt] = *(const f32x4*)(Bq + dir * 512 + (8 * wave + 4 * mt + lhi) * 4);
    }

    // stage u hi-fragments for all 64 steps x 32 batches
    for (int i = tid; i < 2048; i += 1024) {
        const int t = i >> 5, b = i & 31;
        const float2* p = (const float2*)(upd + (size_t)(b0 + b) * 384 + t * 6);
        const float2 a0 = p[0], a1 = p[1], a2 = p[2];
        i32x4 hi4;
        hi4[0] = (int)cvt2bf(a0.x, a0.y);
        hi4[1] = (int)cvt2bf(a1.x, a1.y);
        hi4[2] = (int)cvt2bf(a2.x, a2.y);
        hi4[3] = 0;
        *(i32x4*)(Ub + t * 512 + b * 16) = hi4;
    }
    // zero all h digit planes (read target of step 0 is buf1)
    for (int i = tid; i < 8192; i += 1024) ((int*)Hb)[i] = 0;

    // addresses: read buf1 at s=0, write buf0; toggle = XOR 0x1000; digit imm +8192, kc imm +64
    int ra[2], wa[2];
    #pragma unroll
    for (int g = 0; g < 2; g++) {
        ra[g] = g * 16384 + 4096 + l15 * 144 + lhi * 16;
        wa[g] = g * 16384 + l15 * 144 + 8 * wave + 2 * lhi;
    }
    float c00 = 0.0f, c01 = 0.0f, c10 = 0.0f, c11 = 0.0f;
    __syncthreads();

    const i32x4 zi = {0, 0, 0, 0};

    #pragma unroll 1
    for (int s = 0; s < 64; ++s) {
        const int t = dir ? (63 - s) : s;
        const int ub = t * 512;

        // u fragments: lanes lhi>0 read same bytes (their A-weights are 0 -> dont care)
        const short8 f1g0 = *(const short8*)(Ub + ub + l15 * 16);
        const short8 f1g1 = *(const short8*)(Ub + ub + 256 + l15 * 16);

        __builtin_amdgcn_s_setprio(1);
        // ---- G0: h digit frags + i8 MFMAs ----
        i32x4 A[2][2], Bc[2][2];
        f32x4 U[2][2];
        {
            const i32x4 h1k0 = *(const i32x4*)(Hb + ra[0]);
            const i32x4 h1k1 = *(const i32x4*)(Hb + ra[0] + 64);
            const i32x4 h2k0 = *(const i32x4*)(Hb + ra[0] + 8192);
            const i32x4 h2k1 = *(const i32x4*)(Hb + ra[0] + 8256);
            U[0][0] = __builtin_amdgcn_mfma_f32_16x16x32_bf16(awu[0], f1g0, bias[0], 0, 0, 0);
            U[0][1] = __builtin_amdgcn_mfma_f32_16x16x32_bf16(awu[1], f1g0, bias[1], 0, 0, 0);
            #pragma unroll
            for (int mt = 0; mt < 2; mt++) {
                i32x4 a = __builtin_amdgcn_mfma_i32_16x16x64_i8(wd1[mt][0], h1k0, zi, 0, 0, 0);
                a = __builtin_amdgcn_mfma_i32_16x16x64_i8(wd1[mt][1], h1k1, a, 0, 0, 0);
                i32x4 b = __builtin_amdgcn_mfma_i32_16x16x64_i8(wd1[mt][0], h2k0, zi, 0, 0, 0);
                b = __builtin_amdgcn_mfma_i32_16x16x64_i8(wd1[mt][1], h2k1, b, 0, 0, 0);
                b = __builtin_amdgcn_mfma_i32_16x16x64_i8(wd2[mt][0], h1k0, b, 0, 0, 0);
                b = __builtin_amdgcn_mfma_i32_16x16x64_i8(wd2[mt][1], h1k1, b, 0, 0, 0);
                A[0][mt] = a; Bc[0][mt] = b;
            }
        }
        // ---- G1 ----
        {
            const i32x4 h1k0 = *(const i32x4*)(Hb + ra[1]);
            const i32x4 h1k1 = *(const i32x4*)(Hb + ra[1] + 64);
            const i32x4 h2k0 = *(const i32x4*)(Hb + ra[1] + 8192);
            const i32x4 h2k1 = *(const i32x4*)(Hb + ra[1] + 8256);
            U[1][0] = __builtin_amdgcn_mfma_f32_16x16x32_bf16(awu[0], f1g1, bias[0], 0, 0, 0);
            U[1][1] = __builtin_amdgcn_mfma_f32_16x16x32_bf16(awu[1], f1g1, bias[1], 0, 0, 0);
            #pragma unroll
            for (int mt = 0; mt < 2; mt++) {
                i32x4 a = __builtin_amdgcn_mfma_i32_16x16x64_i8(wd1[mt][0], h1k0, zi, 0, 0, 0);
                a = __builtin_amdgcn_mfma_i32_16x16x64_i8(wd1[mt][1], h1k1, a, 0, 0, 0);
                i32x4 b = __builtin_amdgcn_mfma_i32_16x16x64_i8(wd1[mt][0], h2k0, zi, 0, 0, 0);
                b = __builtin_amdgcn_mfma_i32_16x16x64_i8(wd1[mt][1], h2k1, b, 0, 0, 0);
                b = __builtin_amdgcn_mfma_i32_16x16x64_i8(wd2[mt][0], h1k0, b, 0, 0, 0);
                b = __builtin_amdgcn_mfma_i32_16x16x64_i8(wd2[mt][1], h1k1, b, 0, 0, 0);
                A[1][mt] = a; Bc[1][mt] = b;
            }
        }
        __builtin_amdgcn_s_setprio(0);

        // ---- cells + h digit writes ----
        #pragma unroll
        for (int g = 0; g < 2; g++) {
            int d1[2], d2[2];
            float ho[2];
            #pragma unroll
            for (int mt = 0; mt < 2; mt++) {
                f32x4 z;
                #pragma unroll
                for (int i = 0; i < 4; i++)
                    z[i] = U[g][mt][i] + (float)A[g][mt][i] * 0x1p-16f
                                       + (float)Bc[g][mt][i] * 0x1p-23f;
                float& cc = (g == 0) ? (mt == 0 ? c00 : c01) : (mt == 0 ? c10 : c11);
                float h;
                cell_update(z, cc, h);
                ho[mt] = h;
                const float a = h * 64.0f;
                const float r1 = rintf(a);
                d1[mt] = (int)r1;
                d2[mt] = (int)rintf((a - r1) * 128.0f);
            }
            if (s < 63) {
                *(unsigned short*)(Hb + wa[g]) =
                    (unsigned short)((d1[0] & 0xff) | ((d1[1] & 0xff) << 8));
                *(unsigned short*)(Hb + wa[g] + 8192) =
                    (unsigned short)((d2[0] & 0xff) | ((d2[1] & 0xff) << 8));
            } else {
                float* o = hout + ((size_t)dir * B_TOTAL + b0 + g * 16 + l15) * 128;
                o[8 * wave + lhi]     = ho[0];
                o[8 * wave + 4 + lhi] = ho[1];
            }
        }
        ra[0] ^= 0x1000; ra[1] ^= 0x1000;
        wa[0] ^= 0x1000; wa[1] ^= 0x1000;
        __syncthreads();
    }
}

// ---------------- Kernel C: final FC ----------------
__global__ __launch_bounds__(256) void k_final(
    const float* __restrict__ hout,        // [2][B][128]
    const float* __restrict__ device_idx,  // [B]
    const float* __restrict__ fc_w,        // [257]
    const float* __restrict__ fc_b,        // [1]
    float* __restrict__ y)                 // [B]
{
    const int wave = threadIdx.x >> 6;
    const int lane = threadIdx.x & 63;
    const int b = blockIdx.x * 4 + wave;
    const float* hf = hout + (size_t)b * 128;
    const float* hb = hout + ((size_t)B_TOTAL + b) * 128;
    float p = fc_w[1 + lane]        * hf[lane]
            + fc_w[1 + 64 + lane]   * hf[64 + lane]
            + fc_w[129 + lane]      * hb[lane]
            + fc_w[129 + 64 + lane] * hb[64 + lane];
    #pragma unroll
    for (int off = 32; off; off >>= 1) p += __shfl_xor(p, off, 64);
    if (lane == 0) y[b] = p + fc_w[0] * device_idx[b] + fc_b[0];
}

extern "C" void kernel_launch(void* const* d_in, const int* in_sizes, int n_in,
                              void* d_out, int out_size, void* d_ws, size_t ws_size,
                              hipStream_t stream) {
    const float* device_idx = (const float*)d_in[0];
    const float* matrix     = (const float*)d_in[1];
    const float* features   = (const float*)d_in[2];
    const float* Wi_f = (const float*)d_in[3];
    const float* Wh_f = (const float*)d_in[4];
    const float* bi_f = (const float*)d_in[5];
    const float* bh_f = (const float*)d_in[6];
    const float* Wi_b = (const float*)d_in[7];
    const float* Wh_b = (const float*)d_in[8];
    const float* bi_b = (const float*)d_in[9];
    const float* bh_b = (const float*)d_in[10];
    const float* fc_w = (const float*)d_in[11];
    const float* fc_b = (const float*)d_in[12];
    float* out = (float*)d_out;

    float* ws = (float*)d_ws;
    float*          upd  = ws;                               // 1,572,864 floats
    signed char*    Wd1  = (signed char*)(ws + 1572864);     // 131,072 bytes
    signed char*    Wd2  = (signed char*)(ws + 1605632);     // 131,072 bytes
    unsigned short* AwU  = (unsigned short*)(ws + 1638400);  //  32,768 ushorts
    float*          Bq   = ws + 1654784;                     //   1,024 floats
    float*          hout = ws + 1655808;                     // 1,048,576 floats

    hipLaunchKernelGGL(k_neighbor_mean, dim3(B_TOTAL), dim3(256), 0, stream,
                       matrix, features, upd);
    hipLaunchKernelGGL(k_wprep4, dim3(644), dim3(256), 0, stream,
                       Wi_f, Wh_f, bi_f, bh_f, Wi_b, Wh_b, bi_b, bh_b,
                       Wd1, Wd2, AwU, Bq);
    hipLaunchKernelGGL(k_lstm7, dim3(B_TOTAL / 32, 2), dim3(1024), 0, stream,
                       upd, Wd1, Wd2, AwU, Bq, hout);
    hipLaunchKernelGGL(k_final, dim3(B_TOTAL / 4), dim3(256), 0, stream,
                       hout, device_idx, fc_w, fc_b, out);
}

// Round 7
// 163.157 us; speedup vs baseline: 4.3622x; 1.2058x over previous
//
#include <hip/hip_runtime.h>
#include <hip/hip_bf16.h>

#define B_TOTAL 4096
#define LOG2E 1.44269504088896f

typedef short short8 __attribute__((ext_vector_type(8)));
typedef float f32x4 __attribute__((ext_vector_type(4)));
typedef int   i32x4 __attribute__((ext_vector_type(4)));

__device__ __forceinline__ unsigned short rne_bf16(float x) {
    unsigned int u = __float_as_uint(x);
    unsigned int r = (u + 0x7fffu + ((u >> 16) & 1u)) >> 16;
    return (unsigned short)r;
}
__device__ __forceinline__ unsigned int cvt2bf(float lo, float hi) {
    unsigned int r;
    asm("v_cvt_pk_bf16_f32 %0, %1, %2" : "=v"(r) : "v"(lo), "v"(hi));
    return r;
}

// ---------------- Kernel A: neighbor mean ----------------
__global__ __launch_bounds__(256) void k_neighbor_mean(
    const float* __restrict__ matrix,   // [B,64,64]
    const float* __restrict__ features, // [B,64,6]
    float* __restrict__ upd)            // [B,64,6]
{
    __shared__ float adj[64][65];
    __shared__ float fx[64][6];
    const int b = blockIdx.x;
    const int tid = threadIdx.x;
    const float* mb_ = matrix + (size_t)b * 4096;
    for (int idx = tid; idx < 4096; idx += 256) adj[idx >> 6][idx & 63] = mb_[idx];
    const float* fb = features + (size_t)b * 384;
    for (int idx = tid; idx < 384; idx += 256) fx[idx / 6][idx % 6] = fb[idx];
    __syncthreads();
    if (tid < 64) {
        const int i = tid;
        float s0=0,s1=0,s2=0,s3=0,s4=0,s5=0,cnt=0;
        for (int j = 0; j < 64; j++) {
            float m = adj[i][j] > 0.0f ? 1.0f : 0.0f;
            cnt += m;
            s0 += m*fx[j][0]; s1 += m*fx[j][1]; s2 += m*fx[j][2];
            s3 += m*fx[j][3]; s4 += m*fx[j][4]; s5 += m*fx[j][5];
        }
        const float inv = 1.0f / (cnt + 1.0f);
        float* o = upd + (size_t)b * 384 + i * 6;
        o[0]=(s0+fx[i][0])*inv; o[1]=(s1+fx[i][1])*inv; o[2]=(s2+fx[i][2])*inv;
        o[3]=(s3+fx[i][3])*inv; o[4]=(s4+fx[i][4])*inv; o[5]=(s5+fx[i][5])*inv;
    }
}

// ---------------- Kernel W: weights -> i8 digit A-fragments (log2e-folded) ----------------
// Wd1/Wd2 [dir 2][mtg 32][kc 2][lane 64][e 16] i8:
//   n = mtg*16 + (lane&15), j = (n&3)*128 + (n>>2)   (n = 4*hu + gate)
//   ks = kc*64 + 16*(lane>>4) + e; hu_src = 8*(ks>>3) + 4*(ks&1) + ((ks&7)>>1)
//   a = Wh[j*128+hu_src] * 512*LOG2E (== 256*2*LOG2E, gate-uniform);
//   d1 = rint(a), d2 = rint((a-d1)*128)
// AwU [dir 2][mtg 32][lane 64][e 8] bf16 : Wi * (gate==2 ? 2L : L); nonzero only lane>>4==0 && e<6
// Bq  [dir 2][n 512] f32 : (bi+bh) * (gate==2 ? 2L : L)
__global__ __launch_bounds__(256) void k_wprep5(
    const float* __restrict__ Wi_f, const float* __restrict__ Wh_f,
    const float* __restrict__ bi_f, const float* __restrict__ bh_f,
    const float* __restrict__ Wi_b, const float* __restrict__ Wh_b,
    const float* __restrict__ bi_b, const float* __restrict__ bh_b,
    signed char* __restrict__ Wd1, signed char* __restrict__ Wd2,
    unsigned short* __restrict__ AwU, float* __restrict__ BqO)
{
    const int idx = blockIdx.x * 256 + threadIdx.x;   // 0..164863
    if (idx < 131072) {
        const int dir = idx >> 16;
        const int r = idx & 65535;
        const int mtg = r >> 11;
        const int kc  = (r >> 10) & 1;
        const int l   = (r >> 4) & 63;
        const int e   = r & 15;
        const int n = mtg * 16 + (l & 15);
        const int j = ((n & 3) << 7) + (n >> 2);
        const int ks = kc * 64 + 16 * (l >> 4) + e;   // 0..127
        const int hu = 8 * (ks >> 3) + 4 * (ks & 1) + ((ks & 7) >> 1);
        const float w = (dir ? Wh_b : Wh_f)[j * 128 + hu];
        const float a = w * (512.0f * LOG2E);
        const float r1 = rintf(a);
        Wd1[idx] = (signed char)(int)r1;
        Wd2[idx] = (signed char)(int)rintf((a - r1) * 128.0f);
    } else if (idx < 163840) {
        const int i2 = idx - 131072;       // 0..32767
        const int dir = i2 >> 14;
        const int r = i2 & 16383;
        const int mtg = r >> 9, l = (r >> 3) & 63, e = r & 7;
        const int n = mtg * 16 + (l & 15);
        const int j = ((n & 3) << 7) + (n >> 2);
        const float sc = ((n & 3) == 2) ? 2.0f * LOG2E : LOG2E;
        float w = 0.0f;
        if ((l >> 4) == 0 && e < 6) w = (dir ? Wi_b : Wi_f)[j * 6 + e] * sc;
        AwU[i2] = rne_bf16(w);
    } else if (idx < 164864) {
        const int i2 = idx - 163840;       // 0..1023
        const int dir = i2 >> 9;
        const int n = i2 & 511;
        const int j = ((n & 3) << 7) + (n >> 2);
        const float sc = ((n & 3) == 2) ? 2.0f * LOG2E : LOG2E;
        BqO[i2] = ((dir ? bi_b : bi_f)[j] + (dir ? bh_b : bh_f)[j]) * sc;
    }
}

// ---------------- Kernel B: group-pipelined i8 MFMA bi-LSTM ----------------
// grid (128, 2), block 1024 (16 waves), 1 block/CU.
// Wave owns mtg {2w,2w+1} (hu 8w..8w+7) x 32 batches (groups g0=b0..b0+15, g1=+16).
// Interval iv: [z-assemble group gc=iv&1 from accs issued last interval] ->
//              [issue 14 MFMAs for group gi=gc^1, step (iv+1)>>1] ->
//              [gate/cell/encode for gc under the MFMA shadow] -> barrier.
__global__ __launch_bounds__(1024) void k_lstm8(
    const float* __restrict__ upd,          // [4096][64][6]
    const signed char* __restrict__ Wd1,    // [2][32][2][64][16]
    const signed char* __restrict__ Wd2,    // [2][32][2][64][16]
    const unsigned short* __restrict__ AwU, // [2][32][64][8]
    const float* __restrict__ Bq,           // [2][512]
    float* __restrict__ hout)               // [2][4096][128]
{
    // H: byte = g*16384 + digit*8192 + buf*4096 + row(l15)*144 + col(p(hu))
    __shared__ i32x4 HsV[2048];   // 32 KB
    // U: byte = g*16384 + t*256 + b*16  (bf16x8 {u0..u5,0,0})
    __shared__ i32x4 UsV[2048];   // 32 KB
    char* Hb = (char*)HsV;
    char* Ub = (char*)UsV;
    const int tid  = threadIdx.x;
    const int wave = tid >> 6;
    const int lane = tid & 63;
    const int dir  = blockIdx.y;
    const int b0   = blockIdx.x * 32;
    const int l15  = lane & 15;
    const int lhi  = lane >> 4;
    const int hu0  = 8 * wave + lhi, hu1 = hu0 + 4;

    // persistent: wd 32 + awu 8 + bias 8 + c 4 = 52 VGPRs
    i32x4 wd1[2][2], wd2[2][2];
    short8 awu[2];
    f32x4 bias[2];
    #pragma unroll
    for (int mt = 0; mt < 2; mt++) {
        const int mtg = 2 * wave + mt;
        #pragma unroll
        for (int kc = 0; kc < 2; kc++) {
            wd1[mt][kc] = *(const i32x4*)(Wd1 + dir * 65536 + mtg * 2048 + kc * 1024 + lane * 16);
            wd2[mt][kc] = *(const i32x4*)(Wd2 + dir * 65536 + mtg * 2048 + kc * 1024 + lane * 16);
        }
        awu[mt]  = *(const short8*)(AwU + dir * 16384 + mtg * 512 + lane * 8);
        bias[mt] = *(const f32x4*)(Bq + dir * 512 + mtg * 16 + 4 * lhi);
    }

    // stage u hi-fragments: 64 steps x 32 batches
    for (int i = tid; i < 2048; i += 1024) {
        const int t = i >> 5, b = i & 31;
        const float2* p = (const float2*)(upd + (size_t)(b0 + b) * 384 + t * 6);
        const float2 a0 = p[0], a1 = p[1], a2 = p[2];
        i32x4 v;
        v[0] = (int)cvt2bf(a0.x, a0.y);
        v[1] = (int)cvt2bf(a1.x, a1.y);
        v[2] = (int)cvt2bf(a2.x, a2.y);
        v[3] = 0;
        *(i32x4*)(Ub + (b >> 4) * 16384 + t * 256 + (b & 15) * 16) = v;
    }
    // zero all h digit planes
    for (int i = tid; i < 8192; i += 1024) ((int*)Hb)[i] = 0;

    int ra[2], wa[2];
    #pragma unroll
    for (int g = 0; g < 2; g++) {
        ra[g] = g * 16384 + 4096 + l15 * 144 + lhi * 16;        // read buf1 first
        wa[g] = g * 16384 + l15 * 144 + 8 * wave + 2 * lhi;     // write buf0 first
    }
    float cs[2][2] = {{0.0f, 0.0f}, {0.0f, 0.0f}};
    f32x4 Ua[2][2];
    i32x4 Aa[2][2], Ba[2][2];
    __syncthreads();

    const i32x4 zi = {0, 0, 0, 0};

    // prologue: issue group 0, step 0 (h = zeros)
    {
        const int tt = dir ? 63 : 0;
        const short8 fu = *(const short8*)(Ub + tt * 256 + l15 * 16);
        const i32x4 h1k0 = *(const i32x4*)(Hb + ra[0]);
        const i32x4 h1k1 = *(const i32x4*)(Hb + ra[0] + 64);
        const i32x4 h2k0 = *(const i32x4*)(Hb + ra[0] + 8192);
        const i32x4 h2k1 = *(const i32x4*)(Hb + ra[0] + 8256);
        ra[0] ^= 0x1000;
        #pragma unroll
        for (int mt = 0; mt < 2; mt++) {
            Ua[0][mt] = __builtin_amdgcn_mfma_f32_16x16x32_bf16(awu[mt], fu, bias[mt], 0, 0, 0);
            i32x4 a = __builtin_amdgcn_mfma_i32_16x16x64_i8(wd1[mt][0], h1k0, zi, 0, 0, 0);
            a = __builtin_amdgcn_mfma_i32_16x16x64_i8(wd1[mt][1], h1k1, a, 0, 0, 0);
            i32x4 b = __builtin_amdgcn_mfma_i32_16x16x64_i8(wd1[mt][0], h2k0, zi, 0, 0, 0);
            b = __builtin_amdgcn_mfma_i32_16x16x64_i8(wd1[mt][1], h2k1, b, 0, 0, 0);
            b = __builtin_amdgcn_mfma_i32_16x16x64_i8(wd2[mt][0], h1k0, b, 0, 0, 0);
            b = __builtin_amdgcn_mfma_i32_16x16x64_i8(wd2[mt][1], h1k1, b, 0, 0, 0);
            Aa[0][mt] = a; Ba[0][mt] = b;
        }
    }

    #pragma unroll 2
    for (int iv = 0; iv < 128; ++iv) {
        const int gc = iv & 1;          // group whose cells complete this interval
        const int sc = iv >> 1;

        // ---- z assembly for gc (frees its acc regs early) ----
        float z[2][4];
        #pragma unroll
        for (int mt = 0; mt < 2; mt++)
            #pragma unroll
            for (int i = 0; i < 4; i++) {
                const int T = (Aa[gc][mt][i] << 7) + Ba[gc][mt][i];
                z[mt][i] = fmaf((float)T, (i == 2) ? 0x1p-21f : 0x1p-22f, Ua[gc][mt][i]);
            }

        // ---- issue next group's MFMAs (overlaps the cell math below) ----
        if (iv < 127) {
            const int gi = gc ^ 1;
            const int si = (iv + 1) >> 1;
            const int tt = dir ? (63 - si) : si;
            const short8 fu = *(const short8*)(Ub + gi * 16384 + tt * 256 + l15 * 16);
            const i32x4 h1k0 = *(const i32x4*)(Hb + ra[gi]);
            const i32x4 h1k1 = *(const i32x4*)(Hb + ra[gi] + 64);
            const i32x4 h2k0 = *(const i32x4*)(Hb + ra[gi] + 8192);
            const i32x4 h2k1 = *(const i32x4*)(Hb + ra[gi] + 8256);
            ra[gi] ^= 0x1000;
            __builtin_amdgcn_s_setprio(1);
            #pragma unroll
            for (int mt = 0; mt < 2; mt++) {
                Ua[gi][mt] = __builtin_amdgcn_mfma_f32_16x16x32_bf16(awu[mt], fu, bias[mt], 0, 0, 0);
                i32x4 a = __builtin_amdgcn_mfma_i32_16x16x64_i8(wd1[mt][0], h1k0, zi, 0, 0, 0);
                a = __builtin_amdgcn_mfma_i32_16x16x64_i8(wd1[mt][1], h1k1, a, 0, 0, 0);
                i32x4 b = __builtin_amdgcn_mfma_i32_16x16x64_i8(wd1[mt][0], h2k0, zi, 0, 0, 0);
                b = __builtin_amdgcn_mfma_i32_16x16x64_i8(wd1[mt][1], h2k1, b, 0, 0, 0);
                b = __builtin_amdgcn_mfma_i32_16x16x64_i8(wd2[mt][0], h1k0, b, 0, 0, 0);
                b = __builtin_amdgcn_mfma_i32_16x16x64_i8(wd2[mt][1], h1k1, b, 0, 0, 0);
                Aa[gi][mt] = a; Ba[gi][mt] = b;
            }
            __builtin_amdgcn_s_setprio(0);
        }

        // ---- gates via exp2 + grouped reciprocal (1 rcp / 4 denoms) ----
        float ig[2], fg[2], gg[2], og[2], Dq[2], hh[2];
        #pragma unroll
        for (int mt = 0; mt < 2; mt++) {
            const float D0 = 1.0f + __builtin_amdgcn_exp2f(-z[mt][0]);
            const float D1 = 1.0f + __builtin_amdgcn_exp2f(-z[mt][1]);
            const float D2 = 1.0f + __builtin_amdgcn_exp2f( z[mt][2]);
            const float D3 = 1.0f + __builtin_amdgcn_exp2f(-z[mt][3]);
            const float P2 = D0 * D1, P3 = P2 * D2, P4 = P3 * D3;
            const float r  = __builtin_amdgcn_rcpf(P4);
            const float Q2 = D3 * D2, Q3 = Q2 * D1;
            ig[mt] = r * Q3;
            fg[mt] = (r * Q2) * D0;
            og[mt] = r * P3;
            gg[mt] = fmaf(-2.0f, (r * P2) * D3, 1.0f);
        }
        #pragma unroll
        for (int mt = 0; mt < 2; mt++) {
            cs[gc][mt] = fmaf(fg[mt], cs[gc][mt], ig[mt] * gg[mt]);
            Dq[mt] = 1.0f + __builtin_amdgcn_exp2f(fminf(cs[gc][mt] * (2.0f * LOG2E), 30.0f));
        }
        const float rq = __builtin_amdgcn_rcpf(Dq[0] * Dq[1]);
        hh[0] = og[0] * fmaf(-2.0f, rq * Dq[1], 1.0f);
        hh[1] = og[1] * fmaf(-2.0f, rq * Dq[0], 1.0f);

        // ---- h digit encode (magic-number) + packed writes ----
        if (sc < 63) {
            int d1[2], d2[2];
            #pragma unroll
            for (int mt = 0; mt < 2; mt++) {
                const int t = __float_as_int(fmaf(hh[mt], 8192.0f, 12582912.0f)) - 0x4B400000;
                d1[mt] = (t + 64) >> 7;
                d2[mt] = t - (d1[mt] << 7);
            }
            *(unsigned short*)(Hb + wa[gc]) =
                (unsigned short)__builtin_amdgcn_perm((unsigned)d1[1], (unsigned)d1[0], 0x0400);
            *(unsigned short*)(Hb + wa[gc] + 8192) =
                (unsigned short)__builtin_amdgcn_perm((unsigned)d2[1], (unsigned)d2[0], 0x0400);
        } else {
            float* o = hout + ((size_t)dir * B_TOTAL + b0 + gc * 16 + l15) * 128;
            o[hu0] = hh[0];
            o[hu1] = hh[1];
        }
        wa[gc] ^= 0x1000;
        __syncthreads();
    }
}

// ---------------- Kernel C: final FC ----------------
__global__ __launch_bounds__(256) void k_final(
    const float* __restrict__ hout,        // [2][B][128]
    const float* __restrict__ device_idx,  // [B]
    const float* __restrict__ fc_w,        // [257]
    const float* __restrict__ fc_b,        // [1]
    float* __restrict__ y)                 // [B]
{
    const int wave = threadIdx.x >> 6;
    const int lane = threadIdx.x & 63;
    const int b = blockIdx.x * 4 + wave;
    const float* hf = hout + (size_t)b * 128;
    const float* hb = hout + ((size_t)B_TOTAL + b) * 128;
    float p = fc_w[1 + lane]        * hf[lane]
            + fc_w[1 + 64 + lane]   * hf[64 + lane]
            + fc_w[129 + lane]      * hb[lane]
            + fc_w[129 + 64 + lane] * hb[64 + lane];
    #pragma unroll
    for (int off = 32; off; off >>= 1) p += __shfl_xor(p, off, 64);
    if (lane == 0) y[b] = p + fc_w[0] * device_idx[b] + fc_b[0];
}

extern "C" void kernel_launch(void* const* d_in, const int* in_sizes, int n_in,
                              void* d_out, int out_size, void* d_ws, size_t ws_size,
                              hipStream_t stream) {
    const float* device_idx = (const float*)d_in[0];
    const float* matrix     = (const float*)d_in[1];
    const float* features   = (const float*)d_in[2];
    const float* Wi_f = (const float*)d_in[3];
    const float* Wh_f = (const float*)d_in[4];
    const float* bi_f = (const float*)d_in[5];
    const float* bh_f = (const float*)d_in[6];
    const float* Wi_b = (const float*)d_in[7];
    const float* Wh_b = (const float*)d_in[8];
    const float* bi_b = (const float*)d_in[9];
    const float* bh_b = (const float*)d_in[10];
    const float* fc_w = (const float*)d_in[11];
    const float* fc_b = (const float*)d_in[12];
    float* out = (float*)d_out;

    float* ws = (float*)d_ws;
    float*          upd  = ws;                               // 1,572,864 floats
    signed char*    Wd1  = (signed char*)(ws + 1572864);     // 131,072 bytes
    signed char*    Wd2  = (signed char*)(ws + 1605632);     // 131,072 bytes
    unsigned short* AwU  = (unsigned short*)(ws + 1638400);  //  32,768 ushorts
    float*          Bq   = ws + 1654784;                     //   1,024 floats
    float*          hout = ws + 1655808;                     // 1,048,576 floats

    hipLaunchKernelGGL(k_neighbor_mean, dim3(B_TOTAL), dim3(256), 0, stream,
                       matrix, features, upd);
    hipLaunchKernelGGL(k_wprep5, dim3(644), dim3(256), 0, stream,
                       Wi_f, Wh_f, bi_f, bh_f, Wi_b, Wh_b, bi_b, bh_b,
                       Wd1, Wd2, AwU, Bq);
    hipLaunchKernelGGL(k_lstm8, dim3(B_TOTAL / 32, 2), dim3(1024), 0, stream,
                       upd, Wd1, Wd2, AwU, Bq, hout);
    hipLaunchKernelGGL(k_final, dim3(B_TOTAL / 4), dim3(256), 0, stream,
                       hout, device_idx, fc_w, fc_b, out);
}